// Round 3
// baseline (1009.401 us; speedup 1.0000x reference)
//
#include <hip/hip_runtime.h>
#include <cstdint>

typedef unsigned short u16;
typedef unsigned int u32;
typedef __attribute__((ext_vector_type(4))) float f32x4;
typedef __attribute__((ext_vector_type(8))) __bf16 bf16x8;
typedef __attribute__((ext_vector_type(4))) unsigned short u16x4;
typedef __attribute__((ext_vector_type(8))) unsigned short u16x8;

#define S_LEN 2048
#define BATCH 2
#define NQH 32
#define NKVH 8
#define HD 96
#define EMB 3072
#define QKVN 4608
#define KOFF 3072
#define VOFF 3840

static_assert(sizeof(bf16x8) == 16, "frag size");

__device__ __forceinline__ u16 f2b(float f) {
    u32 u = __float_as_uint(f);
    u32 r = (u + 0x7fffu + ((u >> 16) & 1u)) >> 16;
    return (u16)r;
}
__device__ __forceinline__ float b2f(u16 h) { return __uint_as_float(((u32)h) << 16); }

// Load 8 consecutive elements as a bf16 fragment; F32 sources are converted RNE.
template <bool F32>
__device__ __forceinline__ bf16x8 load_frag8(const void* base, size_t elem) {
    if constexpr (F32) {
        const f32x4* q = (const f32x4*)((const float*)base + elem);
        const f32x4 a = q[0], b = q[1];
        u16x8 t;
#pragma unroll
        for (int i = 0; i < 4; ++i) {
            t[i] = f2b(a[i]);
            t[i + 4] = f2b(b[i]);
        }
        return __builtin_bit_cast(bf16x8, t);
    } else {
        return *(const bf16x8*)((const u16*)base + elem);
    }
}

// C[M,N] = A[M,K] * B[N,K]^T, bf16 MFMA with fp32 accum; A/B may be fp32 (converted
// during staging) or bf16. Output fp32 or bf16. 128x128 tile, BK=32, 4 waves of
// 4x4 16x16x32 MFMAs (m93 structure).
template <bool AF32, bool BF32, bool OUTF32>
__global__ __launch_bounds__(256) void gqa_gemm_bt(const void* __restrict__ Ap,
                                                   const void* __restrict__ Bp,
                                                   void* __restrict__ Cp,
                                                   int M, int N, int K) {
    __shared__ __align__(16) u16 As[128 * 32];
    __shared__ __align__(16) u16 Bs[128 * 32];
    const int tid = threadIdx.x;
    const int wave = tid >> 6, lane = tid & 63;
    const int bm = blockIdx.y * 128, bn = blockIdx.x * 128;
    const int wm = (wave >> 1) * 64, wn = (wave & 1) * 64;
    const int lrow = lane & 15, lk = (lane >> 4) * 8;
    // staging: 512 groups of 8 elems per matrix; thread t -> groups t, t+256
    const int ra = tid >> 2, ca = (tid & 3) * 8;
    const int rb = (tid + 256) >> 2, cb = (tid & 3) * 8;
    f32x4 acc[4][4] = {};

    for (int k0 = 0; k0 < K; k0 += 32) {
        const bf16x8 a0 = load_frag8<AF32>(Ap, (size_t)(bm + ra) * K + k0 + ca);
        const bf16x8 a1 = load_frag8<AF32>(Ap, (size_t)(bm + rb) * K + k0 + cb);
        const bf16x8 b0 = load_frag8<BF32>(Bp, (size_t)(bn + ra) * K + k0 + ca);
        const bf16x8 b1 = load_frag8<BF32>(Bp, (size_t)(bn + rb) * K + k0 + cb);
        __syncthreads();  // previous iteration's readers done before overwrite
        *(bf16x8*)(As + ra * 32 + ca) = a0;
        *(bf16x8*)(As + rb * 32 + cb) = a1;
        *(bf16x8*)(Bs + ra * 32 + ca) = b0;
        *(bf16x8*)(Bs + rb * 32 + cb) = b1;
        __syncthreads();
        bf16x8 af[4], bfr[4];
#pragma unroll
        for (int mi = 0; mi < 4; ++mi)
            af[mi] = *(const bf16x8*)(As + (wm + mi * 16 + lrow) * 32 + lk);
#pragma unroll
        for (int ni = 0; ni < 4; ++ni)
            bfr[ni] = *(const bf16x8*)(Bs + (wn + ni * 16 + lrow) * 32 + lk);
#pragma unroll
        for (int mi = 0; mi < 4; ++mi)
#pragma unroll
            for (int ni = 0; ni < 4; ++ni)
                acc[mi][ni] = __builtin_amdgcn_mfma_f32_16x16x32_bf16(af[mi], bfr[ni],
                                                                      acc[mi][ni], 0, 0, 0);
    }
    // C/D layout: col = lane&15, row = (lane>>4)*4 + reg
    const int orow = bm + wm + (lane >> 4) * 4;
    const int ocol = bn + wn + lrow;
#pragma unroll
    for (int mi = 0; mi < 4; ++mi)
#pragma unroll
        for (int ni = 0; ni < 4; ++ni)
#pragma unroll
            for (int r = 0; r < 4; ++r) {
                const size_t idx = (size_t)(orow + mi * 16 + r) * N + ocol + ni * 16;
                if constexpr (OUTF32)
                    ((float*)Cp)[idx] = acc[mi][ni][r];
                else
                    ((u16*)Cp)[idx] = f2b(acc[mi][ni][r]);
            }
}

// RoPE in-place on q (heads 0..31) and k (heads 32..39) of bf16 qkv ws.
__global__ __launch_bounds__(256) void gqa_rope(u16* __restrict__ qkv,
                                                const int* __restrict__ positions) {
    int i = blockIdx.x * 256 + threadIdx.x;  // BATCH*S_LEN*40*48 exactly
    const int pair = i % 48;
    int t = i / 48;
    const int head = t % (NQH + NKVH);
    const int bs = t / (NQH + NKVH);  // b*S_LEN + s
    const int pos = positions[bs & (S_LEN - 1)];
    const size_t base = (size_t)bs * QKVN + (head < NQH ? head * HD : KOFF + (head - NQH) * HD);
    // inv_freq = 10000^(-2*pair/96)
    const float invf = __expf(-(float)(2 * pair) * (1.0f / 96.0f) * 9.210340371976184f);
    const float ang = (float)pos * invf;
    float sn, cs;
    __sincosf(ang, &sn, &cs);
    const float t1 = b2f(qkv[base + pair]);
    const float t2 = b2f(qkv[base + 48 + pair]);
    qkv[base + pair] = f2b(t1 * cs - t2 * sn);
    qkv[base + 48 + pair] = f2b(t2 * cs + t1 * sn);
}

// Flash-style causal GQA. Block = (qb, qh, b): 64 Q rows, iterate 64-row KV tiles.
// Wave w owns Q rows [w*16, w*16+16).
__global__ __launch_bounds__(256) void gqa_attn(const u16* __restrict__ qkv,
                                                u16* __restrict__ out) {
    __shared__ __align__(16) u16 Qs[64 * 96];
    __shared__ __align__(16) u16 Ks[64 * 96];
    __shared__ __align__(16) u16 VB[2 * 6 * 64 * 8];  // [kk][ns][lane][j] B-frag order
    __shared__ __align__(16) u16 Ps[64 * 64];

    const int tid = threadIdx.x;
    const int wave = tid >> 6, lane = tid & 63;
    const int lrow = lane & 15, lhi = lane >> 4;
    const int qb = blockIdx.x, qh = blockIdx.y, bb = blockIdx.z;
    const int h = qh >> 2;  // GROUPS = 4
    const float scaling = 0.10206207261596575f;  // 96^-0.5

    // ---- stage Q (64 x 96) ----
    const size_t qbase = ((size_t)(bb * S_LEN + qb * 64)) * QKVN + qh * HD;
    for (int q4 = tid; q4 < 1536; q4 += 256) {
        const int e = q4 * 4;
        const int r = e / 96, d = e - r * 96;
        *(u16x4*)(Qs + e) = *(const u16x4*)(qkv + qbase + (size_t)r * QKVN + d);
    }
    __syncthreads();

    // Q A-frags, loop invariant: A[m=lane&15][k=(lane>>4)*8+j]
    bf16x8 aq[3];
#pragma unroll
    for (int kk = 0; kk < 3; ++kk)
        aq[kk] = *(const bf16x8*)(Qs + (wave * 16 + lrow) * 96 + kk * 32 + lhi * 8);

    float m_s[4], l_s[4];
    f32x4 oacc[6] = {};
#pragma unroll
    for (int r = 0; r < 4; ++r) { m_s[r] = -1e30f; l_s[r] = 0.0f; }

    for (int kb = 0; kb <= qb; ++kb) {
        __syncthreads();  // protect Ks/VB/Ps from prior-iteration readers
        // ---- stage K tile and pack V tile into B-fragment order ----
        const size_t kbase = ((size_t)(bb * S_LEN + kb * 64)) * QKVN + KOFF + h * HD;
        const size_t vbase = ((size_t)(bb * S_LEN + kb * 64)) * QKVN + VOFF + h * HD;
        for (int q4 = tid; q4 < 1536; q4 += 256) {
            const int e = q4 * 4;
            const int r = e / 96, d = e - r * 96;
            *(u16x4*)(Ks + e) = *(const u16x4*)(qkv + kbase + (size_t)r * QKVN + d);
            const u16x4 v = *(const u16x4*)(qkv + vbase + (size_t)r * QKVN + d);
            const int kk = r >> 5, kr = r & 31;
            const int lhi2 = kr >> 3, j = kr & 7;
#pragma unroll
            for (int tt = 0; tt < 4; ++tt) {
                const int dd = d + tt;
                const int ns = dd >> 4, llo = dd & 15;
                VB[((kk * 6 + ns) * 64 + lhi2 * 16 + llo) * 8 + j] = v[tt];
            }
        }
        __syncthreads();

        // ---- S = Q K^T (wave's 16 rows x 64 cols) ----
        f32x4 sacc[4] = {};
#pragma unroll
        for (int ni = 0; ni < 4; ++ni)
#pragma unroll
            for (int kk = 0; kk < 3; ++kk) {
                const bf16x8 bk =
                    *(const bf16x8*)(Ks + (ni * 16 + lrow) * 96 + kk * 32 + lhi * 8);
                sacc[ni] = __builtin_amdgcn_mfma_f32_16x16x32_bf16(aq[kk], bk, sacc[ni], 0, 0, 0);
            }

        // scale + causal mask (diagonal tile only)
        float sv[4][4];
#pragma unroll
        for (int ni = 0; ni < 4; ++ni)
#pragma unroll
            for (int r = 0; r < 4; ++r) {
                float s = sacc[ni][r] * scaling;
                if (kb == qb) {
                    const int col = ni * 16 + lrow;
                    const int row = wave * 16 + lhi * 4 + r;
                    if (col > row) s = -1e30f;
                }
                sv[ni][r] = s;
            }

        // row max across 64 cols (4 regs in-lane + 16-lane shfl reduce)
        float alpha[4];
#pragma unroll
        for (int r = 0; r < 4; ++r) {
            float m = fmaxf(fmaxf(sv[0][r], sv[1][r]), fmaxf(sv[2][r], sv[3][r]));
#pragma unroll
            for (int off = 1; off < 16; off <<= 1)
                m = fmaxf(m, __shfl_xor(m, off, 16));
            const float mn = fmaxf(m_s[r], m);
            alpha[r] = __expf(m_s[r] - mn);
            m_s[r] = mn;
        }

        // P = exp(S - m), row sums, write P (bf16) for A-layout reread
        float rs[4] = {0.f, 0.f, 0.f, 0.f};
#pragma unroll
        for (int ni = 0; ni < 4; ++ni)
#pragma unroll
            for (int r = 0; r < 4; ++r) {
                const float p = __expf(sv[ni][r] - m_s[r]);
                rs[r] += p;
                Ps[(wave * 16 + lhi * 4 + r) * 64 + ni * 16 + lrow] = f2b(p);
            }
#pragma unroll
        for (int r = 0; r < 4; ++r) {
            float s = rs[r];
#pragma unroll
            for (int off = 1; off < 16; off <<= 1) s += __shfl_xor(s, off, 16);
            l_s[r] = l_s[r] * alpha[r] + s;
        }
        // rescale O
#pragma unroll
        for (int ns = 0; ns < 6; ++ns)
#pragma unroll
            for (int r = 0; r < 4; ++r) oacc[ns][r] *= alpha[r];

        __syncthreads();  // Ps/VB visibility before fragment re-read

        // ---- O += P V ----
#pragma unroll
        for (int kk = 0; kk < 2; ++kk) {
            const bf16x8 ap = *(const bf16x8*)(Ps + (wave * 16 + lrow) * 64 + kk * 32 + lhi * 8);
#pragma unroll
            for (int ns = 0; ns < 6; ++ns) {
                const bf16x8 bv = *(const bf16x8*)(VB + ((kk * 6 + ns) * 64 + lane) * 8);
                oacc[ns] = __builtin_amdgcn_mfma_f32_16x16x32_bf16(ap, bv, oacc[ns], 0, 0, 0);
            }
        }
    }

    // ---- epilogue: normalize and store (b, s, NQ*HD) bf16 ----
    const size_t obase = ((size_t)(bb * S_LEN + qb * 64)) * EMB + qh * HD;
#pragma unroll
    for (int r = 0; r < 4; ++r) {
        const float inv_l = 1.0f / l_s[r];
        const int row = wave * 16 + lhi * 4 + r;
#pragma unroll
        for (int ns = 0; ns < 6; ++ns)
            out[obase + (size_t)row * EMB + ns * 16 + lrow] = f2b(oacc[ns][r] * inv_l);
    }
}

extern "C" void kernel_launch(void* const* d_in, const int* in_sizes, int n_in,
                              void* d_out, int out_size, void* d_ws, size_t ws_size,
                              hipStream_t stream) {
    const float* x = (const float*)d_in[0];      // (2,2048,3072) fp32
    const int* positions = (const int*)d_in[1];  // (2048,) int32
    // d_in[2]: mask — known causal triu, unused
    const float* W_qkv = (const float*)d_in[3];  // (4608,3072) fp32
    const float* W_o = (const float*)d_in[4];    // (3072,3072) fp32
    float* out = (float*)d_out;                  // (2,2048,3072) fp32

    u16* qkv_ws = (u16*)d_ws;                     // 4096*4608 bf16 = 37.7 MB
    u16* attn_ws = qkv_ws + (size_t)4096 * QKVN;  // 4096*3072 bf16 = 25.2 MB

    const int M = BATCH * S_LEN;  // 4096

    // 1) qkv = x @ W_qkv^T : fp32 in -> bf16 out
    gqa_gemm_bt<true, true, false>
        <<<dim3(QKVN / 128, M / 128), 256, 0, stream>>>(x, W_qkv, qkv_ws, M, QKVN, EMB);
    // 2) RoPE in-place on q,k (bf16)
    gqa_rope<<<(BATCH * S_LEN * (NQH + NKVH) * 48) / 256, 256, 0, stream>>>(qkv_ws, positions);
    // 3) causal GQA attention -> attn_ws (b,s,3072) bf16
    gqa_attn<<<dim3(S_LEN / 64, NQH, BATCH), 256, 0, stream>>>(qkv_ws, attn_ws);
    // 4) out = attn @ W_o^T : bf16 x fp32 -> fp32 out
    gqa_gemm_bt<false, true, true>
        <<<dim3(EMB / 128, M / 128), 256, 0, stream>>>(attn_ws, W_o, out, M, EMB, EMB);
}

// Round 4
// 910.793 us; speedup vs baseline: 1.1083x; 1.1083x over previous
//
#include <hip/hip_runtime.h>
#include <cstdint>

typedef unsigned short u16;
typedef unsigned int u32;
typedef __attribute__((ext_vector_type(4))) float f32x4;
typedef __attribute__((ext_vector_type(8))) __bf16 bf16x8;
typedef __attribute__((ext_vector_type(4))) unsigned short u16x4;
typedef __attribute__((ext_vector_type(8))) unsigned short u16x8;
typedef __attribute__((ext_vector_type(4))) unsigned int u32x4;

#define S_LEN 2048
#define BATCH 2
#define NQH 32
#define NKVH 8
#define HD 96
#define EMB 3072
#define QKVN 4608
#define KOFF 3072
#define VOFF 3840

__device__ __forceinline__ u16 f2b(float f) {
    u32 u = __float_as_uint(f);
    u32 r = (u + 0x7fffu + ((u >> 16) & 1u)) >> 16;
    return (u16)r;
}
__device__ __forceinline__ float b2f(u16 h) { return __uint_as_float(((u32)h) << 16); }

// ---------------- fp32 -> bf16 bulk convert ----------------
__global__ __launch_bounds__(256) void conv_f2b(const float* __restrict__ in,
                                                u16* __restrict__ outp, int n8) {
    const int i = blockIdx.x * 256 + threadIdx.x;
    if (i >= n8) return;
    const f32x4* q = (const f32x4*)(in + (size_t)i * 8);
    const f32x4 a = q[0], b = q[1];
    u16x8 t;
#pragma unroll
    for (int j = 0; j < 4; ++j) {
        t[j] = f2b(a[j]);
        t[j + 4] = f2b(b[j]);
    }
    *(u16x8*)(outp + (size_t)i * 8) = t;
}

// ---------------- GEMM: C[M,N] = A[M,K] * B[N,K]^T ----------------
template <bool F32>
__device__ __forceinline__ bf16x8 load_frag8(const void* base, size_t elem) {
    if constexpr (F32) {
        const f32x4* q = (const f32x4*)((const float*)base + elem);
        const f32x4 a = q[0], b = q[1];
        u16x8 t;
#pragma unroll
        for (int i = 0; i < 4; ++i) {
            t[i] = f2b(a[i]);
            t[i + 4] = f2b(b[i]);
        }
        return __builtin_bit_cast(bf16x8, t);
    } else {
        return *(const bf16x8*)((const u16*)base + elem);
    }
}

template <bool AF32, bool BF32, bool OUTF32>
__global__ __launch_bounds__(256) void gqa_gemm_bt(const void* __restrict__ Ap,
                                                   const void* __restrict__ Bp,
                                                   void* __restrict__ Cp,
                                                   int M, int N, int K) {
    __shared__ __align__(16) u16 As[128 * 32];
    __shared__ __align__(16) u16 Bs[128 * 32];
    const int tid = threadIdx.x;
    const int wave = tid >> 6, lane = tid & 63;
    const int bm = blockIdx.y * 128, bn = blockIdx.x * 128;
    const int wm = (wave >> 1) * 64, wn = (wave & 1) * 64;
    const int lrow = lane & 15, lk = (lane >> 4) * 8;
    const int ra = tid >> 2, ca = (tid & 3) * 8;
    const int rb = (tid + 256) >> 2, cb = (tid & 3) * 8;
    f32x4 acc[4][4] = {};

    for (int k0 = 0; k0 < K; k0 += 32) {
        const bf16x8 a0 = load_frag8<AF32>(Ap, (size_t)(bm + ra) * K + k0 + ca);
        const bf16x8 a1 = load_frag8<AF32>(Ap, (size_t)(bm + rb) * K + k0 + cb);
        const bf16x8 b0 = load_frag8<BF32>(Bp, (size_t)(bn + ra) * K + k0 + ca);
        const bf16x8 b1 = load_frag8<BF32>(Bp, (size_t)(bn + rb) * K + k0 + cb);
        __syncthreads();
        *(bf16x8*)(As + ra * 32 + ca) = a0;
        *(bf16x8*)(As + rb * 32 + cb) = a1;
        *(bf16x8*)(Bs + ra * 32 + ca) = b0;
        *(bf16x8*)(Bs + rb * 32 + cb) = b1;
        __syncthreads();
        bf16x8 af[4], bfr[4];
#pragma unroll
        for (int mi = 0; mi < 4; ++mi)
            af[mi] = *(const bf16x8*)(As + (wm + mi * 16 + lrow) * 32 + lk);
#pragma unroll
        for (int ni = 0; ni < 4; ++ni)
            bfr[ni] = *(const bf16x8*)(Bs + (wn + ni * 16 + lrow) * 32 + lk);
#pragma unroll
        for (int mi = 0; mi < 4; ++mi)
#pragma unroll
            for (int ni = 0; ni < 4; ++ni)
                acc[mi][ni] = __builtin_amdgcn_mfma_f32_16x16x32_bf16(af[mi], bfr[ni],
                                                                      acc[mi][ni], 0, 0, 0);
    }
    const int orow = bm + wm + (lane >> 4) * 4;
    const int ocol = bn + wn + lrow;
#pragma unroll
    for (int mi = 0; mi < 4; ++mi)
#pragma unroll
        for (int ni = 0; ni < 4; ++ni)
#pragma unroll
            for (int r = 0; r < 4; ++r) {
                const size_t idx = (size_t)(orow + mi * 16 + r) * N + ocol + ni * 16;
                if constexpr (OUTF32)
                    ((float*)Cp)[idx] = acc[mi][ni][r];
                else
                    ((u16*)Cp)[idx] = f2b(acc[mi][ni][r]);
            }
}

// ---------------- RoPE in-place on q,k of bf16 qkv ----------------
__global__ __launch_bounds__(256) void gqa_rope(u16* __restrict__ qkv,
                                                const int* __restrict__ positions) {
    int i = blockIdx.x * 256 + threadIdx.x;
    const int pair = i % 48;
    int t = i / 48;
    const int head = t % (NQH + NKVH);
    const int bs = t / (NQH + NKVH);
    const int pos = positions[bs & (S_LEN - 1)];
    const size_t base = (size_t)bs * QKVN + (head < NQH ? head * HD : KOFF + (head - NQH) * HD);
    const float invf = __expf(-(float)(2 * pair) * (1.0f / 96.0f) * 9.210340371976184f);
    const float ang = (float)pos * invf;
    float sn, cs;
    __sincosf(ang, &sn, &cs);
    const float t1 = b2f(qkv[base + pair]);
    const float t2 = b2f(qkv[base + 48 + pair]);
    qkv[base + pair] = f2b(t1 * cs - t2 * sn);
    qkv[base + 48 + pair] = f2b(t2 * cs + t1 * sn);
}

// ---------------- Flash GQA, S^T formulation ----------------
// Block = (qb: 64 q-rows, kv-head, batch); wave w = q-head kvh*4+w, all 64 rows.
// S^T = K.Q^T so C-layout col = q; softmax state is per-lane scalar; O^T = V^T.P^T.
__global__ __launch_bounds__(256) void gqa_attn2(const u16* __restrict__ qkv,
                                                 u16* __restrict__ out) {
    __shared__ __align__(16) u16 Qs[4][64 * 96];  // per-head Q, pre-scaled
    __shared__ __align__(16) u16 Ks[64 * 96];
    __shared__ __align__(16) u16 Vt[96 * 72];  // V^T, row stride 72 (16B aligned)

    const int tid = threadIdx.x;
    const int wave = tid >> 6, lane = tid & 63;
    const int lrow = lane & 15, lhi = lane >> 4;
    const int qb = 31 - blockIdx.x;  // longest blocks first
    const int kvh = blockIdx.y, bb = blockIdx.z;
    const int qh = kvh * 4 + wave;
    const float c = 0.10206207261596575f;  // 96^-0.5 folded into Q

    // stage Q for all 4 heads of the group, pre-scaled
    const size_t qrowbase = (size_t)(bb * S_LEN + qb * 64) * QKVN + (size_t)kvh * 4 * 96;
    for (int u = tid; u < 3072; u += 256) {
        const int oct = u % 12, row = (u / 12) % 64, hh = u / 768;
        u16x8 q8 = *(const u16x8*)(qkv + qrowbase + (size_t)row * QKVN + hh * 96 + oct * 8);
        u16x8 o8;
#pragma unroll
        for (int i = 0; i < 8; ++i) o8[i] = f2b(b2f(q8[i]) * c);
        *(u16x8*)(&Qs[hh][row * 96 + oct * 8]) = o8;
    }

    float m_s[4], l_s[4];
    f32x4 oacc[6][4] = {};  // O^T: [d-tile][q-tile], lane: d=lhi*4+r, q=lrow
#pragma unroll
    for (int qt = 0; qt < 4; ++qt) { m_s[qt] = -1e30f; l_s[qt] = 0.0f; }

    const int s0 = lrow + ((lane & 16) ? 32 : 0);  // shfl src for B-frag dw0/dw1
    const int s1 = s0 + 16;                        // dw2/dw3
    const bool khi = (lane & 32) != 0;             // lhi>>1: selects kt pair

    for (int kb = 0; kb <= qb; ++kb) {
        __syncthreads();  // staging buffers free (also covers Q staging on iter 0)
        const size_t kbase = (size_t)(bb * S_LEN + kb * 64) * QKVN + KOFF + kvh * 96;
        const size_t vbase = (size_t)(bb * S_LEN + kb * 64) * QKVN + VOFF + kvh * 96;
        for (int u = tid; u < 768; u += 256) {
            const int oct = u % 12, row = u / 12;
            *(u16x8*)(Ks + row * 96 + oct * 8) =
                *(const u16x8*)(qkv + kbase + (size_t)row * QKVN + oct * 8);
        }
        for (int u = tid; u < 768; u += 256) {
            const int d = u % 96, so8 = u / 96;
            u16x8 v8;
#pragma unroll
            for (int j = 0; j < 8; ++j) v8[j] = qkv[vbase + (size_t)(so8 * 8 + j) * QKVN + d];
            *(u16x8*)(Vt + d * 72 + so8 * 8) = v8;
        }
        __syncthreads();

        // K A-frags: A[m=kseq][k=d], held for all kt
        bf16x8 ka[4][3];
#pragma unroll
        for (int kt = 0; kt < 4; ++kt)
#pragma unroll
            for (int kd = 0; kd < 3; ++kd)
                ka[kt][kd] = *(const bf16x8*)(Ks + (kt * 16 + lrow) * 96 + kd * 32 + lhi * 8);

        const bool diag = (kb == qb);
        u32 bp[4][2][4];  // P^T B-frags [qt][kk][dword]

#pragma unroll
        for (int qt = 0; qt < 4; ++qt) {
            // Q B-frags: B[k=d][n=q] read as Q[q][d]
            bf16x8 bq[3];
#pragma unroll
            for (int kd = 0; kd < 3; ++kd)
                bq[kd] = *(const bf16x8*)(&Qs[wave][(qt * 16 + lrow) * 96 + kd * 32 + lhi * 8]);
            f32x4 sacc[4] = {};
#pragma unroll
            for (int kt = 0; kt < 4; ++kt) {
                if (diag && kt > qt) continue;  // fully-masked tile
#pragma unroll
                for (int kd = 0; kd < 3; ++kd)
                    sacc[kt] = __builtin_amdgcn_mfma_f32_16x16x32_bf16(ka[kt][kd], bq[kd],
                                                                       sacc[kt], 0, 0, 0);
            }
            // scores (pre-scaled by c), causal mask on diagonal kt==qt
            float p[4][4];
            float mx = -3e38f;
#pragma unroll
            for (int kt = 0; kt < 4; ++kt) {
                const bool live = !diag || (kt <= qt);
#pragma unroll
                for (int r = 0; r < 4; ++r) {
                    float s = live ? sacc[kt][r] : -3e38f;
                    if (diag && kt == qt && (lhi * 4 + r) > lrow) s = -3e38f;
                    p[kt][r] = s;
                    mx = fmaxf(mx, s);
                }
            }
            mx = fmaxf(mx, __shfl_xor(mx, 16));
            mx = fmaxf(mx, __shfl_xor(mx, 32));
            const float mn = fmaxf(m_s[qt], mx);
            const float alpha = __expf(m_s[qt] - mn);
            m_s[qt] = mn;
            float rs = 0.0f;
#pragma unroll
            for (int kt = 0; kt < 4; ++kt) {
                const bool live = !diag || (kt <= qt);
#pragma unroll
                for (int r = 0; r < 4; ++r) {
                    const float pv = live ? __expf(p[kt][r] - mn) : 0.0f;
                    p[kt][r] = pv;
                    rs += pv;
                }
            }
            rs += __shfl_xor(rs, 16);
            rs += __shfl_xor(rs, 32);
            l_s[qt] = l_s[qt] * alpha + rs;
#pragma unroll
            for (int dt = 0; dt < 6; ++dt)
#pragma unroll
                for (int r = 0; r < 4; ++r) oacc[dt][qt][r] *= alpha;
            // pack p to bf16 pairs: pk[kt][i] = (p[2i], p[2i+1])
            u32 pk[4][2];
#pragma unroll
            for (int kt = 0; kt < 4; ++kt) {
                pk[kt][0] = (u32)f2b(p[kt][0]) | ((u32)f2b(p[kt][1]) << 16);
                pk[kt][1] = (u32)f2b(p[kt][2]) | ((u32)f2b(p[kt][3]) << 16);
            }
            // C-layout -> B-frag via shuffles: dword dw from lane s0/s1, reg pk[kk*2+khi][dw&1]
#pragma unroll
            for (int kk = 0; kk < 2; ++kk) {
                const u32 a0 = (u32)__shfl((int)pk[kk * 2][0], s0, 64);
                const u32 b0 = (u32)__shfl((int)pk[kk * 2 + 1][0], s0, 64);
                const u32 a1 = (u32)__shfl((int)pk[kk * 2][1], s0, 64);
                const u32 b1 = (u32)__shfl((int)pk[kk * 2 + 1][1], s0, 64);
                const u32 a2 = (u32)__shfl((int)pk[kk * 2][0], s1, 64);
                const u32 b2 = (u32)__shfl((int)pk[kk * 2 + 1][0], s1, 64);
                const u32 a3 = (u32)__shfl((int)pk[kk * 2][1], s1, 64);
                const u32 b3 = (u32)__shfl((int)pk[kk * 2 + 1][1], s1, 64);
                bp[qt][kk][0] = khi ? b0 : a0;
                bp[qt][kk][1] = khi ? b1 : a1;
                bp[qt][kk][2] = khi ? b2 : a2;
                bp[qt][kk][3] = khi ? b3 : a3;
            }
        }

        // O^T += V^T . P^T
#pragma unroll
        for (int dt = 0; dt < 6; ++dt) {
            bf16x8 va[2];
#pragma unroll
            for (int kk = 0; kk < 2; ++kk)
                va[kk] = *(const bf16x8*)(Vt + (dt * 16 + lrow) * 72 + kk * 32 + lhi * 8);
#pragma unroll
            for (int qt = 0; qt < 4; ++qt)
#pragma unroll
                for (int kk = 0; kk < 2; ++kk) {
                    const u32x4 bv = {bp[qt][kk][0], bp[qt][kk][1], bp[qt][kk][2], bp[qt][kk][3]};
                    oacc[dt][qt] = __builtin_amdgcn_mfma_f32_16x16x32_bf16(
                        va[kk], __builtin_bit_cast(bf16x8, bv), oacc[dt][qt], 0, 0, 0);
                }
        }
    }

    // epilogue: lane holds O^T[d=dt*16+lhi*4+r][q=qt*16+lrow]; store (b,s,NQ*HD) bf16
    const size_t obase = (size_t)(bb * S_LEN + qb * 64) * EMB + qh * 96;
#pragma unroll
    for (int qt = 0; qt < 4; ++qt) {
        const float inv = 1.0f / l_s[qt];
        const size_t rbase = obase + (size_t)(qt * 16 + lrow) * EMB;
#pragma unroll
        for (int dt = 0; dt < 6; ++dt)
#pragma unroll
            for (int rp = 0; rp < 2; ++rp) {
                const u32 pair = (u32)f2b(oacc[dt][qt][2 * rp] * inv) |
                                 ((u32)f2b(oacc[dt][qt][2 * rp + 1] * inv) << 16);
                *(u32*)(out + rbase + dt * 16 + lhi * 4 + 2 * rp) = pair;
            }
    }
}

extern "C" void kernel_launch(void* const* d_in, const int* in_sizes, int n_in,
                              void* d_out, int out_size, void* d_ws, size_t ws_size,
                              hipStream_t stream) {
    const float* x = (const float*)d_in[0];
    const int* positions = (const int*)d_in[1];
    const float* W_qkv = (const float*)d_in[3];
    const float* W_o = (const float*)d_in[4];
    float* out = (float*)d_out;

    const int M = BATCH * S_LEN;  // 4096
    const size_t QKV_E = (size_t)M * QKVN;
    const size_t ATT_E = (size_t)M * EMB;
    const size_t X_E = (size_t)M * EMB;
    const size_t WQ_E = (size_t)QKVN * EMB;
    const size_t WO_E = (size_t)EMB * EMB;

    u16* qkv_ws = (u16*)d_ws;
    u16* attn_ws = qkv_ws + QKV_E;
    u16* xb = attn_ws + ATT_E;
    u16* wqb = xb + X_E;
    u16* wob = wqb + WQ_E;
    const size_t need = (QKV_E + ATT_E + X_E + WQ_E + WO_E) * 2;

    if (ws_size >= need) {
        conv_f2b<<<(int)(X_E / 8 + 255) / 256, 256, 0, stream>>>(x, xb, (int)(X_E / 8));
        conv_f2b<<<(int)(WQ_E / 8 + 255) / 256, 256, 0, stream>>>(W_qkv, wqb, (int)(WQ_E / 8));
        conv_f2b<<<(int)(WO_E / 8 + 255) / 256, 256, 0, stream>>>(W_o, wob, (int)(WO_E / 8));
        gqa_gemm_bt<false, false, false>
            <<<dim3(QKVN / 128, M / 128), 256, 0, stream>>>(xb, wqb, qkv_ws, M, QKVN, EMB);
        gqa_rope<<<(BATCH * S_LEN * (NQH + NKVH) * 48) / 256, 256, 0, stream>>>(qkv_ws, positions);
        gqa_attn2<<<dim3(S_LEN / 64, NKVH, BATCH), 256, 0, stream>>>(qkv_ws, attn_ws);
        gqa_gemm_bt<false, false, true>
            <<<dim3(EMB / 128, M / 128), 256, 0, stream>>>(attn_ws, wob, out, M, EMB, EMB);
    } else {
        gqa_gemm_bt<true, true, false>
            <<<dim3(QKVN / 128, M / 128), 256, 0, stream>>>(x, W_qkv, qkv_ws, M, QKVN, EMB);
        gqa_rope<<<(BATCH * S_LEN * (NQH + NKVH) * 48) / 256, 256, 0, stream>>>(qkv_ws, positions);
        gqa_attn2<<<dim3(S_LEN / 64, NKVH, BATCH), 256, 0, stream>>>(qkv_ws, attn_ws);
        gqa_gemm_bt<false, true, true>
            <<<dim3(EMB / 128, M / 128), 256, 0, stream>>>(attn_ws, W_o, out, M, EMB, EMB);
    }
}

// Round 6
// 656.264 us; speedup vs baseline: 1.5381x; 1.3878x over previous
//
#include <hip/hip_runtime.h>
#include <cstdint>

typedef unsigned short u16;
typedef unsigned int u32;
typedef __attribute__((ext_vector_type(4))) float f32x4;
typedef __attribute__((ext_vector_type(8))) __bf16 bf16x8;
typedef __attribute__((ext_vector_type(8))) unsigned short u16x8;
typedef __attribute__((ext_vector_type(4))) unsigned int u32x4;

#define S_LEN 2048
#define BATCH 2
#define NQH 32
#define NKVH 8
#define HD 96
#define EMB 3072
#define QKVN 4608
#define KOFF 3072
#define VOFF 3840

__device__ __forceinline__ u16 f2b(float f) {
    u32 u = __float_as_uint(f);
    u32 r = (u + 0x7fffu + ((u >> 16) & 1u)) >> 16;
    return (u16)r;
}
__device__ __forceinline__ float b2f(u16 h) { return __uint_as_float(((u32)h) << 16); }
__device__ __forceinline__ u32 pk2(float a, float b) {
    return (u32)f2b(a) | ((u32)f2b(b) << 16);
}

// ---------------- fp32 -> bf16 bulk convert ----------------
__global__ __launch_bounds__(256) void conv_f2b(const float* __restrict__ in,
                                                u16* __restrict__ outp, int n8) {
    const int i = blockIdx.x * 256 + threadIdx.x;
    if (i >= n8) return;
    const f32x4* q = (const f32x4*)(in + (size_t)i * 8);
    const f32x4 a = q[0], b = q[1];
    u16x8 t;
#pragma unroll
    for (int j = 0; j < 4; ++j) {
        t[j] = f2b(a[j]);
        t[j + 4] = f2b(b[j]);
    }
    *(u16x8*)(outp + (size_t)i * 8) = t;
}

// ---------------- GEMM: C[M,N] = A[M,K] * B[N,K]^T ----------------
template <bool F32>
__device__ __forceinline__ bf16x8 load_frag8(const void* base, size_t elem) {
    if constexpr (F32) {
        const f32x4* q = (const f32x4*)((const float*)base + elem);
        const f32x4 a = q[0], b = q[1];
        u16x8 t;
#pragma unroll
        for (int i = 0; i < 4; ++i) {
            t[i] = f2b(a[i]);
            t[i + 4] = f2b(b[i]);
        }
        return __builtin_bit_cast(bf16x8, t);
    } else {
        return *(const bf16x8*)((const u16*)base + elem);
    }
}

template <bool AF32, bool BF32, bool OUTF32>
__global__ __launch_bounds__(256) void gqa_gemm_bt(const void* __restrict__ Ap,
                                                   const void* __restrict__ Bp,
                                                   void* __restrict__ Cp,
                                                   int M, int N, int K) {
    __shared__ __align__(16) u16 As[128 * 32];
    __shared__ __align__(16) u16 Bs[128 * 32];
    const int tid = threadIdx.x;
    const int wave = tid >> 6, lane = tid & 63;
    const int bm = blockIdx.y * 128, bn = blockIdx.x * 128;
    const int wm = (wave >> 1) * 64, wn = (wave & 1) * 64;
    const int lrow = lane & 15, lk = (lane >> 4) * 8;
    const int ra = tid >> 2, ca = (tid & 3) * 8;
    const int rb = (tid + 256) >> 2, cb = (tid & 3) * 8;
    f32x4 acc[4][4] = {};

    for (int k0 = 0; k0 < K; k0 += 32) {
        const bf16x8 a0 = load_frag8<AF32>(Ap, (size_t)(bm + ra) * K + k0 + ca);
        const bf16x8 a1 = load_frag8<AF32>(Ap, (size_t)(bm + rb) * K + k0 + cb);
        const bf16x8 b0 = load_frag8<BF32>(Bp, (size_t)(bn + ra) * K + k0 + ca);
        const bf16x8 b1 = load_frag8<BF32>(Bp, (size_t)(bn + rb) * K + k0 + cb);
        __syncthreads();
        *(bf16x8*)(As + ra * 32 + ca) = a0;
        *(bf16x8*)(As + rb * 32 + cb) = a1;
        *(bf16x8*)(Bs + ra * 32 + ca) = b0;
        *(bf16x8*)(Bs + rb * 32 + cb) = b1;
        __syncthreads();
        bf16x8 af[4], bfr[4];
#pragma unroll
        for (int mi = 0; mi < 4; ++mi)
            af[mi] = *(const bf16x8*)(As + (wm + mi * 16 + lrow) * 32 + lk);
#pragma unroll
        for (int ni = 0; ni < 4; ++ni)
            bfr[ni] = *(const bf16x8*)(Bs + (wn + ni * 16 + lrow) * 32 + lk);
#pragma unroll
        for (int mi = 0; mi < 4; ++mi)
#pragma unroll
            for (int ni = 0; ni < 4; ++ni)
                acc[mi][ni] = __builtin_amdgcn_mfma_f32_16x16x32_bf16(af[mi], bfr[ni],
                                                                      acc[mi][ni], 0, 0, 0);
    }
    const int orow = bm + wm + (lane >> 4) * 4;
    const int ocol = bn + wn + lrow;
#pragma unroll
    for (int mi = 0; mi < 4; ++mi)
#pragma unroll
        for (int ni = 0; ni < 4; ++ni)
#pragma unroll
            for (int r = 0; r < 4; ++r) {
                const size_t idx = (size_t)(orow + mi * 16 + r) * N + ocol + ni * 16;
                if constexpr (OUTF32)
                    ((float*)Cp)[idx] = acc[mi][ni][r];
                else
                    ((u16*)Cp)[idx] = f2b(acc[mi][ni][r]);
            }
}

// ---------------- RoPE in-place on q,k of bf16 qkv ----------------
__global__ __launch_bounds__(256) void gqa_rope(u16* __restrict__ qkv,
                                                const int* __restrict__ positions) {
    int i = blockIdx.x * 256 + threadIdx.x;
    const int pair = i % 48;
    int t = i / 48;
    const int head = t % (NQH + NKVH);
    const int bs = t / (NQH + NKVH);
    const int pos = positions[bs & (S_LEN - 1)];
    const size_t base = (size_t)bs * QKVN + (head < NQH ? head * HD : KOFF + (head - NQH) * HD);
    const float invf = __expf(-(float)(2 * pair) * (1.0f / 96.0f) * 9.210340371976184f);
    const float ang = (float)pos * invf;
    float sn, cs;
    __sincosf(ang, &sn, &cs);
    const float t1 = b2f(qkv[base + pair]);
    const float t2 = b2f(qkv[base + 48 + pair]);
    qkv[base + pair] = f2b(t1 * cs - t2 * sn);
    qkv[base + 48 + pair] = f2b(t2 * cs + t1 * sn);
}

// ---------------- Flash GQA v3: 32-row q-tiles, oversubscribed grid ----------------
// 1024 blocks of 4 waves. Block bx: qt32 = 63 - bx/16 (big work first), (kvh,bb)=bx%16.
// Wave w = q-head kvh*4+w, q-rows [qt32*32, +32) as 2 sub-tiles of 16.
// S^T = K.Q^T (C-layout col = q, per-lane softmax state); O^T = V^T.P^T.
__global__ __launch_bounds__(256) void gqa_attn3(const u16* __restrict__ qkv,
                                                 u16* __restrict__ out) {
    __shared__ __align__(16) u16 Ks[64 * 96];  // 12 KB
    __shared__ __align__(16) u16 Vt[96 * 72];  // 13.5 KB, V^T rows padded to 72

    const int tid = threadIdx.x;
    const int wave = tid >> 6, lane = tid & 63;
    const int lrow = lane & 15, lhi = lane >> 4;
    const int bx = blockIdx.x;
    const int qt32 = 63 - (bx >> 4);
    const int kvh = (bx >> 1) & 7, bb = bx & 1;
    const int qh = kvh * 4 + wave;
    const int srow0 = bb * S_LEN + qt32 * 32;    // first global q-row
    const int kb_last = (qt32 * 32 + 31) >> 6;   // KV tiles 0..kb_last
    const float cl2 = 0.10206207261596575f * 1.4426950408889634f;  // scale * log2(e)

    // Q B-frags in registers: bq[qt][kd], lane holds Q[q=qt*16+lrow][d=kd*32+lhi*8+j]
    bf16x8 bq[2][3];
#pragma unroll
    for (int qt = 0; qt < 2; ++qt)
#pragma unroll
        for (int kd = 0; kd < 3; ++kd)
            bq[qt][kd] = *(const bf16x8*)(qkv + (size_t)(srow0 + qt * 16 + lrow) * QKVN +
                                          qh * 96 + kd * 32 + lhi * 8);

    float m_s[2] = {-3e38f, -3e38f}, l_s[2] = {0.0f, 0.0f};
    f32x4 oacc[6][2] = {};  // O^T: lane d=dt*16+lhi*4+r, q=qt*16+lrow

    const int s0 = lrow + ((lane & 16) ? 32 : 0);  // shfl src for B-frag dw0/dw1
    const int s1 = s0 + 16;                        // dw2/dw3
    const bool khi = (lane & 32) != 0;

    const size_t kvrow0 = (size_t)(bb * S_LEN) * QKVN;
    for (int kb = 0; kb <= kb_last; ++kb) {
        __syncthreads();  // staging buffers free
        const size_t kbase = kvrow0 + (size_t)(kb * 64) * QKVN + KOFF + kvh * 96;
        const size_t vbase = kvrow0 + (size_t)(kb * 64) * QKVN + VOFF + kvh * 96;
        for (int u = tid; u < 768; u += 256) {
            const int oct = u % 12, row = u / 12;
            *(u16x8*)(Ks + row * 96 + oct * 8) =
                *(const u16x8*)(qkv + kbase + (size_t)row * QKVN + oct * 8);
        }
        for (int u = tid; u < 768; u += 256) {
            const int d = u % 96, so8 = u / 96;
            u16x8 v8;
#pragma unroll
            for (int j = 0; j < 8; ++j) v8[j] = qkv[vbase + (size_t)(so8 * 8 + j) * QKVN + d];
            *(u16x8*)(Vt + d * 72 + so8 * 8) = v8;
        }
        __syncthreads();

        // K A-frags: A[m=kseq][k=d]
        bf16x8 ka[4][3];
#pragma unroll
        for (int kt = 0; kt < 4; ++kt)
#pragma unroll
            for (int kd = 0; kd < 3; ++kd)
                ka[kt][kd] = *(const bf16x8*)(Ks + (kt * 16 + lrow) * 96 + kd * 32 + lhi * 8);

        const int qoff = qt32 * 32 - kb * 64;  // >=64 for kb<kb_last; 0 or 32 on diagonal
        const bool lastkb = (kb == kb_last);
        u32 bp[2][2][4];  // P^T B-frags

#pragma unroll
        for (int qt = 0; qt < 2; ++qt) {
            const int qrelmax = qoff + qt * 16 + 15;
            f32x4 sacc[4] = {};
#pragma unroll
            for (int kt = 0; kt < 4; ++kt) {
                if (lastkb && kt * 16 > qrelmax) continue;  // fully-masked tile
#pragma unroll
                for (int kd = 0; kd < 3; ++kd)
                    sacc[kt] = __builtin_amdgcn_mfma_f32_16x16x32_bf16(ka[kt][kd], bq[qt][kd],
                                                                       sacc[kt], 0, 0, 0);
            }
            float p[4][4];
            float mx = -3e38f;
            if (lastkb) {
                const int qrel = qoff + qt * 16 + lrow;
#pragma unroll
                for (int kt = 0; kt < 4; ++kt)
#pragma unroll
                    for (int r = 0; r < 4; ++r) {
                        const bool live = (kt * 16 + lhi * 4 + r) <= qrel;
                        const float s = live ? sacc[kt][r] : -3e38f;
                        p[kt][r] = s;
                        mx = fmaxf(mx, s);
                    }
            } else {
#pragma unroll
                for (int kt = 0; kt < 4; ++kt)
#pragma unroll
                    for (int r = 0; r < 4; ++r) {
                        p[kt][r] = sacc[kt][r];
                        mx = fmaxf(mx, sacc[kt][r]);
                    }
            }
            mx = fmaxf(mx, __shfl_xor(mx, 16));
            mx = fmaxf(mx, __shfl_xor(mx, 32));
            const float mn = fmaxf(m_s[qt], mx);
            const float alpha = exp2f((m_s[qt] - mn) * cl2);
            m_s[qt] = mn;
            float rs = 0.0f;
#pragma unroll
            for (int kt = 0; kt < 4; ++kt)
#pragma unroll
                for (int r = 0; r < 4; ++r) {
                    const float pv = exp2f((p[kt][r] - mn) * cl2);  // masked -> exp2(-inf)=0
                    p[kt][r] = pv;
                    rs += pv;
                }
            rs += __shfl_xor(rs, 16);
            rs += __shfl_xor(rs, 32);
            l_s[qt] = l_s[qt] * alpha + rs;
#pragma unroll
            for (int dt = 0; dt < 6; ++dt)
#pragma unroll
                for (int r = 0; r < 4; ++r) oacc[dt][qt][r] *= alpha;
            // pack + C-layout -> B-frag shuffle transpose (verified map from R4 kernel)
            u32 pk[4][2];
#pragma unroll
            for (int kt = 0; kt < 4; ++kt) {
                pk[kt][0] = pk2(p[kt][0], p[kt][1]);
                pk[kt][1] = pk2(p[kt][2], p[kt][3]);
            }
#pragma unroll
            for (int kk = 0; kk < 2; ++kk) {
                const u32 a0 = (u32)__shfl((int)pk[kk * 2][0], s0, 64);
                const u32 b0 = (u32)__shfl((int)pk[kk * 2 + 1][0], s0, 64);
                const u32 a1 = (u32)__shfl((int)pk[kk * 2][1], s0, 64);
                const u32 b1 = (u32)__shfl((int)pk[kk * 2 + 1][1], s0, 64);
                const u32 a2 = (u32)__shfl((int)pk[kk * 2][0], s1, 64);
                const u32 b2 = (u32)__shfl((int)pk[kk * 2 + 1][0], s1, 64);
                const u32 a3 = (u32)__shfl((int)pk[kk * 2][1], s1, 64);
                const u32 b3 = (u32)__shfl((int)pk[kk * 2 + 1][1], s1, 64);
                bp[qt][kk][0] = khi ? b0 : a0;
                bp[qt][kk][1] = khi ? b1 : a1;
                bp[qt][kk][2] = khi ? b2 : a2;
                bp[qt][kk][3] = khi ? b3 : a3;
            }
        }

        // O^T += V^T . P^T
#pragma unroll
        for (int dt = 0; dt < 6; ++dt) {
            bf16x8 va[2];
#pragma unroll
            for (int kk = 0; kk < 2; ++kk)
                va[kk] = *(const bf16x8*)(Vt + (dt * 16 + lrow) * 72 + kk * 32 + lhi * 8);
#pragma unroll
            for (int qt = 0; qt < 2; ++qt)
#pragma unroll
                for (int kk = 0; kk < 2; ++kk) {
                    const u32x4 bv = {bp[qt][kk][0], bp[qt][kk][1], bp[qt][kk][2], bp[qt][kk][3]};
                    oacc[dt][qt] = __builtin_amdgcn_mfma_f32_16x16x32_bf16(
                        va[kk], __builtin_bit_cast(bf16x8, bv), oacc[dt][qt], 0, 0, 0);
                }
        }
    }

    // epilogue: lane holds O^T[d=dt*16+lhi*4+r][q=qt*16+lrow]
    const size_t obase = (size_t)srow0 * EMB + qh * 96;
#pragma unroll
    for (int qt = 0; qt < 2; ++qt) {
        const float inv = 1.0f / l_s[qt];
        const size_t rbase = obase + (size_t)(qt * 16 + lrow) * EMB;
#pragma unroll
        for (int dt = 0; dt < 6; ++dt)
#pragma unroll
            for (int rp = 0; rp < 2; ++rp) {
                const u32 pair = pk2(oacc[dt][qt][2 * rp] * inv, oacc[dt][qt][2 * rp + 1] * inv);
                *(u32*)(out + rbase + dt * 16 + lhi * 4 + 2 * rp) = pair;
            }
    }
}

extern "C" void kernel_launch(void* const* d_in, const int* in_sizes, int n_in,
                              void* d_out, int out_size, void* d_ws, size_t ws_size,
                              hipStream_t stream) {
    const float* x = (const float*)d_in[0];
    const int* positions = (const int*)d_in[1];
    const float* W_qkv = (const float*)d_in[3];
    const float* W_o = (const float*)d_in[4];
    float* out = (float*)d_out;

    const int M = BATCH * S_LEN;  // 4096
    const size_t QKV_E = (size_t)M * QKVN;
    const size_t ATT_E = (size_t)M * EMB;
    const size_t X_E = (size_t)M * EMB;
    const size_t WQ_E = (size_t)QKVN * EMB;
    const size_t WO_E = (size_t)EMB * EMB;

    u16* qkv_ws = (u16*)d_ws;
    u16* attn_ws = qkv_ws + QKV_E;
    u16* xb = attn_ws + ATT_E;
    u16* wqb = xb + X_E;
    u16* wob = wqb + WQ_E;
    const size_t need = (QKV_E + ATT_E + X_E + WQ_E + WO_E) * 2;

    if (ws_size >= need) {
        conv_f2b<<<(int)(X_E / 8 + 255) / 256, 256, 0, stream>>>(x, xb, (int)(X_E / 8));
        conv_f2b<<<(int)(WQ_E / 8 + 255) / 256, 256, 0, stream>>>(W_qkv, wqb, (int)(WQ_E / 8));
        conv_f2b<<<(int)(WO_E / 8 + 255) / 256, 256, 0, stream>>>(W_o, wob, (int)(WO_E / 8));
        gqa_gemm_bt<false, false, false>
            <<<dim3(QKVN / 128, M / 128), 256, 0, stream>>>(xb, wqb, qkv_ws, M, QKVN, EMB);
        gqa_rope<<<(BATCH * S_LEN * (NQH + NKVH) * 48) / 256, 256, 0, stream>>>(qkv_ws, positions);
        gqa_attn3<<<dim3(1024), 256, 0, stream>>>(qkv_ws, attn_ws);
        gqa_gemm_bt<false, false, true>
            <<<dim3(EMB / 128, M / 128), 256, 0, stream>>>(attn_ws, wob, out, M, EMB, EMB);
    } else {
        gqa_gemm_bt<true, true, false>
            <<<dim3(QKVN / 128, M / 128), 256, 0, stream>>>(x, W_qkv, qkv_ws, M, QKVN, EMB);
        gqa_rope<<<(BATCH * S_LEN * (NQH + NKVH) * 48) / 256, 256, 0, stream>>>(qkv_ws, positions);
        gqa_attn3<<<dim3(1024), 256, 0, stream>>>(qkv_ws, attn_ws);
        gqa_gemm_bt<false, true, true>
            <<<dim3(EMB / 128, M / 128), 256, 0, stream>>>(attn_ws, W_o, out, M, EMB, EMB);
    }
}